// Round 12
// baseline (93.469 us; speedup 1.0000x reference)
//
#include <hip/hip_runtime.h>
#include <hip/hip_bf16.h>
#include <float.h>

// Problem constants (B, N, M from the reference)
#define B_      8
#define N_      8192
#define M_      8192
#define THREADS 256
#define P       8                    // a-points per thread
#define SPLIT   32                   // M-loop split factor
#define CHUNK   (M_ / SPLIT)         // 256 b-points per block (4 KB LDS)
#define APB     (THREADS * P)        // 2048 a-points per block
#define ATILES  (N_ / APB)           // 4 a-tiles per (batch, dir)
#define NBLOCKS (2 * SPLIT * ATILES * B_)  // 2048 = 8 blocks/CU, 32 waves/CU

// Fused prologue: pack xyz [n,3] -> float4 (x,y,z,|p|^2) for BOTH inputs AND
// init out[i] = FLT_MAX (atomicMin target). n_total = B*(N+M) == out_size.
__global__ void prep_kernel(const float* __restrict__ xyz1,
                            const float* __restrict__ xyz2,
                            float4* __restrict__ pk,      // [B*N] then [B*M]
                            float* __restrict__ out, int n1, int n_total) {
    int i = blockIdx.x * blockDim.x + threadIdx.x;
    if (i < n_total) {
        const float* src = (i < n1) ? (xyz1 + 3 * i) : (xyz2 + 3 * (i - n1));
        float x = src[0], y = src[1], z = src[2];
        pk[i] = make_float4(x, y, z, fmaf(x, x, fmaf(y, y, z * z)));
        out[i] = FLT_MAX;
    }
}

__global__ void init_kernel(float* __restrict__ out, int n) {
    int i = blockIdx.x * blockDim.x + threadIdx.x;
    if (i < n) out[i] = FLT_MAX;
}

// Pure-LDS main kernel with REGISTER DOUBLE-BUFFERING of the b-pair.
// R8 vs R11 showed the wall (~200k cyc) is NOT LDS-pipe throughput (halving
// ds_reads changed nothing) — it's load-to-use serialization: each iter
// stalled ~86 cyc on lgkmcnt before its 112-cyc FMA block. Here the next
// pair's ds_reads are issued BEFORE the current pair's compute, putting the
// latency under the FMAs. Live set ~44 VGPR (<=64 keeps 8 waves/SIMD).
__global__ __launch_bounds__(THREADS, 4) void chamfer_lds(
    const float4* __restrict__ pk1,   // packed xyz1 [B*N]
    const float4* __restrict__ pk2,   // packed xyz2 [B*M]
    float* __restrict__ out)          // [B*N] dist1 then [B*M] dist2
{
    __shared__ float4 sb[CHUNK];      // 4 KB

    int bid = blockIdx.x;
    int dir   = bid & 1;                 bid >>= 1;
    int chunk = bid & (SPLIT - 1);       bid /= SPLIT;
    int atile = bid & (ATILES - 1);      bid /= ATILES;
    int batch = bid;                                      // 0..B_-1

    const float4* Ap = dir ? pk2 : pk1;
    const float4* Bp = (dir ? pk1 : pk2) + batch * M_ + chunk * CHUNK;
    float* o = out + (dir ? (B_ * N_) : 0);

    // stage b-chunk into LDS (coalesced dwordx4, 1 per thread)
    for (int t = threadIdx.x; t < CHUNK; t += THREADS)
        sb[t] = Bp[t];

    const int a0 = batch * N_ + atile * APB + threadIdx.x;

    float ax2[P], ay2[P], az2[P], m[P];
#pragma unroll
    for (int p = 0; p < P; ++p) {
        float4 a = Ap[a0 + p * THREADS];   // coalesced dwordx4
        ax2[p] = -2.0f * a.x;
        ay2[p] = -2.0f * a.y;
        az2[p] = -2.0f * a.z;
        m[p]   = FLT_MAX;
    }

    __syncthreads();

    // register double-buffer: current pair (b0,b1), prefetch pair (n0,n1)
    float4 b0 = sb[0];
    float4 b1 = sb[1];
    for (int j = 0; j < CHUNK - 2; j += 2) {
        float4 n0 = sb[j + 2];    // issued before the FMA block below;
        float4 n1 = sb[j + 3];    // lgkmcnt wait lands after ~112 cyc of VALU
#pragma unroll
        for (int p = 0; p < P; ++p) {
            float t0 = fmaf(az2[p], b0.z, b0.w);
            t0 = fmaf(ay2[p], b0.y, t0);
            t0 = fmaf(ax2[p], b0.x, t0);
            float t1 = fmaf(az2[p], b1.z, b1.w);
            t1 = fmaf(ay2[p], b1.y, t1);
            t1 = fmaf(ax2[p], b1.x, t1);
            asm("v_min3_f32 %0, %0, %1, %2"
                : "+v"(m[p]) : "v"(t0), "v"(t1));
        }
        b0 = n0;
        b1 = n1;
    }
    // final pair
#pragma unroll
    for (int p = 0; p < P; ++p) {
        float t0 = fmaf(az2[p], b0.z, b0.w);
        t0 = fmaf(ay2[p], b0.y, t0);
        t0 = fmaf(ax2[p], b0.x, t0);
        float t1 = fmaf(az2[p], b1.z, b1.w);
        t1 = fmaf(ay2[p], b1.y, t1);
        t1 = fmaf(ax2[p], b1.x, t1);
        asm("v_min3_f32 %0, %0, %1, %2"
            : "+v"(m[p]) : "v"(t0), "v"(t1));
    }

#pragma unroll
    for (int p = 0; p < P; ++p) {
        float4 a = Ap[a0 + p * THREADS];         // reload just for a.w (L2-hot)
        float d = fmaxf(a.w + m[p], 0.0f);       // clamp keeps uint-min valid
        atomicMin((unsigned int*)(o + a0 + p * THREADS), __float_as_uint(d));
    }
}

// Fallback if ws too small: raw reads, scalar math (known-good from R2).
#define FP      8
#define FSPLIT  8
#define FCHUNK  (M_ / FSPLIT)
#define FAPB    (THREADS * FP)
#define FATILES (N_ / FAPB)
#define FNBLOCKS (2 * FSPLIT * FATILES * B_)
__global__ __launch_bounds__(THREADS) void chamfer_raw(
    const float* __restrict__ xyz1,
    const float* __restrict__ xyz2,
    float* __restrict__ out)
{
    int bid = blockIdx.x;
    int dir   = bid & 1;                 bid >>= 1;
    int chunk = bid & (FSPLIT - 1);      bid /= FSPLIT;
    int atile = bid & (FATILES - 1);     bid /= FATILES;
    int batch = bid;

    const float* A  = dir ? xyz2 : xyz1;
    const float* Bp = dir ? xyz1 : xyz2;
    float* o = out + (dir ? (B_ * N_) : 0);

    const int a0 = batch * N_ + atile * FAPB + threadIdx.x;

    float ax2[FP], ay2[FP], az2[FP], aw[FP], m[FP];
#pragma unroll
    for (int p = 0; p < FP; ++p) {
        int idx = a0 + p * THREADS;
        float x = A[3 * idx + 0];
        float y = A[3 * idx + 1];
        float z = A[3 * idx + 2];
        ax2[p] = -2.0f * x;
        ay2[p] = -2.0f * y;
        az2[p] = -2.0f * z;
        aw[p]  = fmaf(x, x, fmaf(y, y, z * z));
        m[p]   = FLT_MAX;
    }

    const float* bp = Bp + 3 * (batch * M_ + chunk * FCHUNK);
#pragma unroll 2
    for (int j = 0; j < FCHUNK; j += 2) {
        float b0x = bp[3 * j + 0], b0y = bp[3 * j + 1], b0z = bp[3 * j + 2];
        float b1x = bp[3 * j + 3], b1y = bp[3 * j + 4], b1z = bp[3 * j + 5];
        float b0w = fmaf(b0x, b0x, fmaf(b0y, b0y, b0z * b0z));
        float b1w = fmaf(b1x, b1x, fmaf(b1y, b1y, b1z * b1z));
#pragma unroll
        for (int p = 0; p < FP; ++p) {
            float t0 = fmaf(ax2[p], b0x, b0w);
            t0 = fmaf(ay2[p], b0y, t0);
            t0 = fmaf(az2[p], b0z, t0);
            float t1 = fmaf(ax2[p], b1x, b1w);
            t1 = fmaf(ay2[p], b1y, t1);
            t1 = fmaf(az2[p], b1z, t1);
            m[p] = fminf(m[p], fminf(t0, t1));
        }
    }

#pragma unroll
    for (int p = 0; p < FP; ++p) {
        float d = fmaxf(aw[p] + m[p], 0.0f);
        atomicMin((unsigned int*)(o + a0 + p * THREADS), __float_as_uint(d));
    }
}

extern "C" void kernel_launch(void* const* d_in, const int* in_sizes, int n_in,
                              void* d_out, int out_size, void* d_ws, size_t ws_size,
                              hipStream_t stream) {
    const float* xyz1 = (const float*)d_in[0];
    const float* xyz2 = (const float*)d_in[1];
    float* out = (float*)d_out;

    const int n_out = B_ * N_ + B_ * M_;   // 131072

    const size_t need = (size_t)(B_ * (N_ + M_)) * sizeof(float4);  // 2 MiB
    if (ws_size >= need) {
        float4* pk1 = (float4*)d_ws;          // [B*N]; pk2 follows at [B*M]
        prep_kernel<<<(n_out + 255) / 256, 256, 0, stream>>>(
            xyz1, xyz2, pk1, out, B_ * N_, n_out);
        chamfer_lds<<<NBLOCKS, THREADS, 0, stream>>>(pk1, pk1 + (size_t)B_ * N_, out);
    } else {
        init_kernel<<<(n_out + 255) / 256, 256, 0, stream>>>(out, n_out);
        chamfer_raw<<<FNBLOCKS, THREADS, 0, stream>>>(xyz1, xyz2, out);
    }
}

// Round 13
// 64.002 us; speedup vs baseline: 1.4604x; 1.4604x over previous
//
#include <hip/hip_runtime.h>
#include <hip/hip_bf16.h>
#include <float.h>

// Problem constants (B, N, M from the reference)
#define B_      8
#define N_      8192
#define M_      8192
#define NSIDE   (B_ * N_)            // 65536 points per side
#define NTOT    (2 * NSIDE)          // 131072
#define THREADS 256
#define WAVES   4
#define PM      4                    // 16-row M-tiles per wave -> 64 rows/wave, 256/block
#define BSPLIT  4                    // b-range split -> 2048 blocks total
#define BCHUNK  (M_ / BSPLIT)        // 2048 b-points per block
#define NTILE   (BCHUNK / 16)        // 128 MFMA b-tiles per block
#define NBLOCKS (2 * BSPLIT * (N_ / (THREADS)) * B_)   // 2*4*32*8 = 2048

typedef _Float16 f16;
typedef f16   f16x8 __attribute__((ext_vector_type(8)));
typedef float f32x4 __attribute__((ext_vector_type(4)));

// B-pack per point: 16 f16 (32 B), K-slots for mfma_f32_16x16x32_f16.
//   k0..7 : [wh, wl, xh, xl, xh, yh, yl, yh]
//   k8..15: [zh, zl, zh, 0, 0, 0, 0, 0]
// Paired against A rows [1, 1, -2xh, -2xh, -2xl, -2yh, -2yh, -2yl | -2zh, -2zh, -2zl, 0...]:
//   D = wh + wl - 2(xh·xh' + xh·xl' + xl·xh' + ...) = |b|^2 - 2 a.b  (err ~1e-5)
__global__ void prep_kernel(const float* __restrict__ xyz1,
                            const float* __restrict__ xyz2,
                            f16* __restrict__ Bpack,   // [NTOT*16]
                            float* __restrict__ aw,    // [NTOT]
                            float* __restrict__ out,   // [NTOT] -> FLT_MAX
                            int n1, int n_total) {
    int i = blockIdx.x * blockDim.x + threadIdx.x;
    if (i >= n_total) return;
    const float* s = (i < n1) ? (xyz1 + 3 * i) : (xyz2 + 3 * (i - n1));
    float x = s[0], y = s[1], z = s[2];
    float w = fmaf(x, x, fmaf(y, y, z * z));
    f16 xh = (f16)x, yh = (f16)y, zh = (f16)z;
    f16 xl = (f16)(x - (float)xh);
    f16 yl = (f16)(y - (float)yh);
    f16 zl = (f16)(z - (float)zh);
    f16 wh = (f16)w;
    f16 wl = (f16)(w - (float)wh);
    f16x8 b0 = {wh, wl, xh, xl, xh, yh, yl, yh};
    f16x8 b1 = {zh, zl, zh, (f16)0, (f16)0, (f16)0, (f16)0, (f16)0};
    *(f16x8*)(Bpack + (size_t)i * 16 + 0) = b0;
    *(f16x8*)(Bpack + (size_t)i * 16 + 8) = b1;
    aw[i]  = w;
    out[i] = FLT_MAX;                 // atomicMin target (graph-safe re-init)
}

__global__ void init_kernel(float* __restrict__ out, int n) {
    int i = blockIdx.x * blockDim.x + threadIdx.x;
    if (i < n) out[i] = FLT_MAX;
}

// MFMA main kernel. Each wave owns PM=4 16-row a-tiles and streams NTILE
// b-tiles (16 pts each) through mfma_f32_16x16x32_f16 (K=11 used of 32).
// C/D layout (verified on gfx950): col = lane&15, row = (lane>>4)*4 + reg.
// A operand: row = lane&15, k = (lane>>4)*8 + j  (lanes 32-63 -> k>=16 -> 0).
// B operand: col = lane&15, k = (lane>>4)*8 + j  (lanes 32-63 duplicate 0-31;
//            their A is zero so values are don't-care but must be finite).
__global__ __launch_bounds__(THREADS, 4) void chamfer_mfma(
    const float* __restrict__ xyz1,
    const float* __restrict__ xyz2,
    const f16*  __restrict__ Bpack,
    const float* __restrict__ aw,
    float* __restrict__ out)
{
    int bid = blockIdx.x;
    int dir   = bid & 1;   bid >>= 1;
    int bs    = bid & 3;   bid >>= 2;   // BSPLIT=4
    int ab    = bid & 31;  bid >>= 5;   // N_/256 = 32 a-blocks
    int batch = bid;                    // 0..7

    const int lane = threadIdx.x & 63;
    const int wv   = threadIdx.x >> 6;
    const int g    = lane >> 4;         // k-group 0..3
    const int c    = lane & 15;

    const int aoff = dir ? NSIDE : 0;           // a-side offset in point space
    const int boff = dir ? 0 : NSIDE;           // b-side offset
    const int abase = batch * N_ + ab * THREADS + wv * 64;  // row base (side-local)

    const float* axyz = (dir ? xyz2 : xyz1);

    // ---- Build A fragments in-kernel from raw f32 coords (once) ----
    f16x8 zf = {(f16)0,(f16)0,(f16)0,(f16)0,(f16)0,(f16)0,(f16)0,(f16)0};
    f16x8 af[PM];
#pragma unroll
    for (int t = 0; t < PM; ++t) {
        int pa = abase + t * 16 + c;            // this lane's a-point (side-local)
        const float* s = axyz + 3 * (size_t)pa;
        float x = s[0], y = s[1], z = s[2];
        f16 xh = (f16)x, yh = (f16)y, zh = (f16)z;
        f16 xl = (f16)(x - (float)xh);
        f16 yl = (f16)(y - (float)yh);
        f16 zl = (f16)(z - (float)zh);
        f16 x2 = (f16)(-2.0f * (float)xh), x2l = (f16)(-2.0f * (float)xl);
        f16 y2 = (f16)(-2.0f * (float)yh), y2l = (f16)(-2.0f * (float)yl);
        f16 z2 = (f16)(-2.0f * (float)zh), z2l = (f16)(-2.0f * (float)zl);
        f16x8 lo = {(f16)1.0f, (f16)1.0f, x2, x2, x2l, y2, y2, y2l};
        f16x8 hi = {z2, z2, z2l, (f16)0, (f16)0, (f16)0, (f16)0, (f16)0};
        af[t] = (g == 0) ? lo : (g == 1) ? hi : zf;
    }

    // ---- B-fragment stream (global, L2-hot; 16B/lane/tile) ----
    const f16* Bp = Bpack + (size_t)(boff + batch * M_ + bs * BCHUNK) * 16;
    const f16* blane = Bp + (size_t)c * 16 + (g & 1) * 8;  // lanes 32-63 dup 0-31

    f32x4 m[PM];
#pragma unroll
    for (int t = 0; t < PM; ++t)
        m[t] = (f32x4){FLT_MAX, FLT_MAX, FLT_MAX, FLT_MAX};

    const f32x4 zero4 = {0.f, 0.f, 0.f, 0.f};

    // register prefetch depth 2; tail over-reads <=1KB past Bpack into aw (valid ws)
    f16x8 bf0 = *(const f16x8*)(blane);
    f16x8 bf1 = *(const f16x8*)(blane + 256);
    for (int it = 0; it < NTILE; ++it) {
        f16x8 cur = bf0;
        bf0 = bf1;
        bf1 = *(const f16x8*)(blane + (size_t)(it + 2) * 256);
#pragma unroll
        for (int t = 0; t < PM; ++t) {
            f32x4 d = __builtin_amdgcn_mfma_f32_16x16x32_f16(af[t], cur, zero4, 0, 0, 0);
            m[t][0] = fminf(m[t][0], d[0]);
            m[t][1] = fminf(m[t][1], d[1]);
            m[t][2] = fminf(m[t][2], d[2]);
            m[t][3] = fminf(m[t][3], d[3]);
        }
    }

    // ---- Reduce over the 16 col-lanes within each k-group, then atomicMin ----
    const float* awp = aw + aoff;
    float* o = out + aoff;   // dir0 -> dist1 at [0,65536), dir1 -> dist2
#pragma unroll
    for (int t = 0; t < PM; ++t) {
        f32x4 mm = m[t];
#pragma unroll
        for (int s = 1; s < 16; s <<= 1) {
            mm[0] = fminf(mm[0], __shfl_xor(mm[0], s));
            mm[1] = fminf(mm[1], __shfl_xor(mm[1], s));
            mm[2] = fminf(mm[2], __shfl_xor(mm[2], s));
            mm[3] = fminf(mm[3], __shfl_xor(mm[3], s));
        }
        if (c < 4) {
            float v = (c == 0) ? mm[0] : (c == 1) ? mm[1] : (c == 2) ? mm[2] : mm[3];
            int row = abase + t * 16 + 4 * g + c;     // row = (lane>>4)*4 + reg
            float dd = fmaxf(awp[row] + v, 0.0f);     // clamp keeps uint-min valid
            atomicMin((unsigned int*)(o + row), __float_as_uint(dd));
        }
    }
}

// Fallback if ws too small: raw reads, scalar math (known-good from R2).
#define FP      8
#define FSPLIT  8
#define FCHUNK  (M_ / FSPLIT)
#define FAPB    (THREADS * FP)
#define FATILES (N_ / FAPB)
#define FNBLOCKS (2 * FSPLIT * FATILES * B_)
__global__ __launch_bounds__(THREADS) void chamfer_raw(
    const float* __restrict__ xyz1,
    const float* __restrict__ xyz2,
    float* __restrict__ out)
{
    int bid = blockIdx.x;
    int dir   = bid & 1;                 bid >>= 1;
    int chunk = bid & (FSPLIT - 1);      bid /= FSPLIT;
    int atile = bid & (FATILES - 1);     bid /= FATILES;
    int batch = bid;

    const float* A  = dir ? xyz2 : xyz1;
    const float* Bp = dir ? xyz1 : xyz2;
    float* o = out + (dir ? (B_ * N_) : 0);

    const int a0 = batch * N_ + atile * FAPB + threadIdx.x;

    float ax2[FP], ay2[FP], az2[FP], aww[FP], mm[FP];
#pragma unroll
    for (int p = 0; p < FP; ++p) {
        int idx = a0 + p * THREADS;
        float x = A[3 * idx + 0];
        float y = A[3 * idx + 1];
        float z = A[3 * idx + 2];
        ax2[p] = -2.0f * x;
        ay2[p] = -2.0f * y;
        az2[p] = -2.0f * z;
        aww[p] = fmaf(x, x, fmaf(y, y, z * z));
        mm[p]  = FLT_MAX;
    }

    const float* bp = Bp + 3 * (batch * M_ + chunk * FCHUNK);
#pragma unroll 2
    for (int j = 0; j < FCHUNK; j += 2) {
        float b0x = bp[3 * j + 0], b0y = bp[3 * j + 1], b0z = bp[3 * j + 2];
        float b1x = bp[3 * j + 3], b1y = bp[3 * j + 4], b1z = bp[3 * j + 5];
        float b0w = fmaf(b0x, b0x, fmaf(b0y, b0y, b0z * b0z));
        float b1w = fmaf(b1x, b1x, fmaf(b1y, b1y, b1z * b1z));
#pragma unroll
        for (int p = 0; p < FP; ++p) {
            float t0 = fmaf(ax2[p], b0x, b0w);
            t0 = fmaf(ay2[p], b0y, t0);
            t0 = fmaf(az2[p], b0z, t0);
            float t1 = fmaf(ax2[p], b1x, b1w);
            t1 = fmaf(ay2[p], b1y, t1);
            t1 = fmaf(az2[p], b1z, t1);
            mm[p] = fminf(mm[p], fminf(t0, t1));
        }
    }

#pragma unroll
    for (int p = 0; p < FP; ++p) {
        float d = fmaxf(aww[p] + mm[p], 0.0f);
        atomicMin((unsigned int*)(o + a0 + p * THREADS), __float_as_uint(d));
    }
}

extern "C" void kernel_launch(void* const* d_in, const int* in_sizes, int n_in,
                              void* d_out, int out_size, void* d_ws, size_t ws_size,
                              hipStream_t stream) {
    const float* xyz1 = (const float*)d_in[0];
    const float* xyz2 = (const float*)d_in[1];
    float* out = (float*)d_out;

    // ws layout: Bpack [NTOT*32B] @0, aw [NTOT*4B] @4MB. +4KB pad for tail overread.
    const size_t bpack_bytes = (size_t)NTOT * 32;
    const size_t need = bpack_bytes + (size_t)NTOT * 4 + 4096;
    if (ws_size >= need) {
        f16*   Bpack = (f16*)d_ws;
        float* aw    = (float*)((char*)d_ws + bpack_bytes);
        prep_kernel<<<(NTOT + 255) / 256, 256, 0, stream>>>(
            xyz1, xyz2, Bpack, aw, out, NSIDE, NTOT);
        chamfer_mfma<<<NBLOCKS, THREADS, 0, stream>>>(xyz1, xyz2, Bpack, aw, out);
    } else {
        init_kernel<<<(NTOT + 255) / 256, 256, 0, stream>>>(out, NTOT);
        chamfer_raw<<<FNBLOCKS, THREADS, 0, stream>>>(xyz1, xyz2, out);
    }
}

// Round 14
// 52.046 us; speedup vs baseline: 1.7959x; 1.2297x over previous
//
#include <hip/hip_runtime.h>
#include <hip/hip_bf16.h>
#include <float.h>

// Problem constants (B, N, M from the reference)
#define B_      8
#define N_      8192
#define M_      8192
#define NSIDE   (B_ * N_)            // 65536 points per side
#define NTOT    (2 * NSIDE)          // 131072
#define THREADS 256
#define PM      2                    // 32-row a-tiles per wave -> 64 rows/wave, 256/block
#define BSPLIT  4                    // b-range split
#define BCHUNK  (M_ / BSPLIT)        // 2048 b-points per block
#define NTILE   (BCHUNK / 32)        // 64 MFMA b-tiles (32 pts each) per block
#define NBLOCKS (2 * BSPLIT * (N_ / THREADS) * B_)   // 2*4*32*8 = 2048

typedef _Float16 f16;
typedef f16   f16x8  __attribute__((ext_vector_type(8)));
typedef float f32x16 __attribute__((ext_vector_type(16)));

// B-pack per point: 16 f16 (32 B) = K-slots (same pack as R13, verified):
//   k0..7 : [wh, wl, xh, xl, xh, yh, yl, yh]
//   k8..15: [zh, zl, zh, 0, 0, 0, 0, 0]
// Against A rows [1, 1, -2xh, -2xh, -2xl, -2yh, -2yh, -2yl | -2zh, -2zh, -2zl, 0..]:
//   D = |b|^2 - 2 a.b + O(lo*lo ~ 1e-7)
__global__ void prep_kernel(const float* __restrict__ xyz1,
                            const float* __restrict__ xyz2,
                            f16* __restrict__ Bpack,   // [NTOT*16]
                            float* __restrict__ aw,    // [NTOT]
                            float* __restrict__ out,   // [NTOT] -> FLT_MAX
                            int n1, int n_total) {
    int i = blockIdx.x * blockDim.x + threadIdx.x;
    if (i >= n_total) return;
    const float* s = (i < n1) ? (xyz1 + 3 * i) : (xyz2 + 3 * (i - n1));
    float x = s[0], y = s[1], z = s[2];
    float w = fmaf(x, x, fmaf(y, y, z * z));
    f16 xh = (f16)x, yh = (f16)y, zh = (f16)z;
    f16 xl = (f16)(x - (float)xh);
    f16 yl = (f16)(y - (float)yh);
    f16 zl = (f16)(z - (float)zh);
    f16 wh = (f16)w;
    f16 wl = (f16)(w - (float)wh);
    f16x8 b0 = {wh, wl, xh, xl, xh, yh, yl, yh};
    f16x8 b1 = {zh, zl, zh, (f16)0, (f16)0, (f16)0, (f16)0, (f16)0};
    *(f16x8*)(Bpack + (size_t)i * 16 + 0) = b0;
    *(f16x8*)(Bpack + (size_t)i * 16 + 8) = b1;
    aw[i]  = w;
    out[i] = FLT_MAX;                 // atomicMin target (graph-safe re-init)
}

__global__ void init_kernel(float* __restrict__ out, int n) {
    int i = blockIdx.x * blockDim.x + threadIdx.x;
    if (i < n) out[i] = FLT_MAX;
}

// 32x32x16 MFMA main kernel. vs R13's 16x16x32: K=16 (our K=11 wastes only
// 5 slots, not 21) and all 64 lanes carry real operands -> pairs per
// matrix-pipe cycle 13.2 -> 31.7. Matrix-pipe cost 33us -> ~14us.
// A operand: row = lane&31, k = (lane>>5)*8 + j.
// B operand: col = lane&31, k = (lane>>5)*8 + j.
// C/D: col = lane&31, row = (reg&3) + 8*(reg>>2) + 4*(lane>>5)  [m74/m101].
__global__ __launch_bounds__(THREADS, 4) void chamfer_mfma32(
    const float* __restrict__ xyz1,
    const float* __restrict__ xyz2,
    const f16*  __restrict__ Bpack,
    const float* __restrict__ aw,
    float* __restrict__ out)
{
    int bid = blockIdx.x;
    int dir   = bid & 1;   bid >>= 1;
    int bs    = bid & (BSPLIT - 1); bid >>= 2;
    int ab    = bid & 31;  bid >>= 5;   // N_/256 = 32 a-blocks
    int batch = bid;                    // 0..7

    const int lane = threadIdx.x & 63;
    const int wv   = threadIdx.x >> 6;
    const int g    = lane >> 5;         // k-half 0/1
    const int c    = lane & 31;         // a-row / b-col within tile

    const int aoff = dir ? NSIDE : 0;
    const int boff = dir ? 0 : NSIDE;
    const int abase = batch * N_ + ab * THREADS + wv * (PM * 32);

    const float* axyz = (dir ? xyz2 : xyz1);

    // ---- A fragments from raw f32 coords ----
    f16x8 af[PM];
#pragma unroll
    for (int t = 0; t < PM; ++t) {
        int pa = abase + t * 32 + c;
        const float* s = axyz + 3 * (size_t)pa;
        float x = s[0], y = s[1], z = s[2];
        f16 xh = (f16)x, yh = (f16)y, zh = (f16)z;
        f16 xl = (f16)(x - (float)xh);
        f16 yl = (f16)(y - (float)yh);
        f16 zl = (f16)(z - (float)zh);
        f16 x2 = (f16)(-2.0f * (float)xh), x2l = (f16)(-2.0f * (float)xl);
        f16 y2 = (f16)(-2.0f * (float)yh), y2l = (f16)(-2.0f * (float)yl);
        f16 z2 = (f16)(-2.0f * (float)zh), z2l = (f16)(-2.0f * (float)zl);
        f16x8 lo = {(f16)1.0f, (f16)1.0f, x2, x2, x2l, y2, y2, y2l};
        f16x8 hi = {z2, z2, z2l, (f16)0, (f16)0, (f16)0, (f16)0, (f16)0};
        af[t] = (g == 0) ? lo : hi;
    }

    // ---- B-fragment stream: tile = 32 points x 16 f16 = 512 f16 = 1 KB ----
    const f16* Bp = Bpack + (size_t)(boff + batch * M_ + bs * BCHUNK) * 16;
    const f16* blane = Bp + (size_t)c * 16 + g * 8;

    f32x16 m[PM];
#pragma unroll
    for (int t = 0; t < PM; ++t)
#pragma unroll
        for (int i = 0; i < 16; ++i) m[t][i] = FLT_MAX;

    const f32x16 zero16 = {0.f,0.f,0.f,0.f,0.f,0.f,0.f,0.f,
                           0.f,0.f,0.f,0.f,0.f,0.f,0.f,0.f};

    // register prefetch depth 4 tiles; tail over-reads <=6KB past the chunk
    // (worst case lands in aw[], valid ws memory — pad accounted below).
    f16x8 b0 = *(const f16x8*)(blane + 0 * 512);
    f16x8 b1 = *(const f16x8*)(blane + 1 * 512);
    f16x8 b2 = *(const f16x8*)(blane + 2 * 512);
    f16x8 b3 = *(const f16x8*)(blane + 3 * 512);
    for (int it = 0; it < NTILE; it += 2) {
        f16x8 c0 = b0, c1 = b1;
        b0 = b2; b1 = b3;
        b2 = *(const f16x8*)(blane + (size_t)(it + 4) * 512);
        b3 = *(const f16x8*)(blane + (size_t)(it + 5) * 512);
#pragma unroll
        for (int t = 0; t < PM; ++t) {
            f32x16 d0 = __builtin_amdgcn_mfma_f32_32x32x16_f16(af[t], c0, zero16, 0, 0, 0);
            f32x16 d1 = __builtin_amdgcn_mfma_f32_32x32x16_f16(af[t], c1, zero16, 0, 0, 0);
#pragma unroll
            for (int i = 0; i < 16; ++i)
                m[t][i] = fminf(m[t][i], fminf(d0[i], d1[i]));   // v_min3 hoped
        }
    }

    // ---- Reduce min over the 32 col-lanes of each half, then atomicMin ----
    const float* awp = aw + aoff;
    float* o = out + aoff;
#pragma unroll
    for (int t = 0; t < PM; ++t) {
        f32x16 mm = m[t];
#pragma unroll
        for (int s = 1; s < 32; s <<= 1) {
#pragma unroll
            for (int i = 0; i < 16; ++i)
                mm[i] = fminf(mm[i], __shfl_xor(mm[i], s));
        }
        // lane c (c<16) takes reg=c via static select chain (no dyn index)
        float val = mm[0];
#pragma unroll
        for (int r = 1; r < 16; ++r) val = (c == r) ? mm[r] : val;
        if (c < 16) {
            int row = abase + t * 32 + (c & 3) + 8 * (c >> 2) + 4 * g;
            float dd = fmaxf(awp[row] + val, 0.0f);   // clamp keeps uint-min valid
            atomicMin((unsigned int*)(o + row), __float_as_uint(dd));
        }
    }
}

// Fallback if ws too small: raw reads, scalar math (known-good from R2).
#define FP      8
#define FSPLIT  8
#define FCHUNK  (M_ / FSPLIT)
#define FAPB    (THREADS * FP)
#define FATILES (N_ / FAPB)
#define FNBLOCKS (2 * FSPLIT * FATILES * B_)
__global__ __launch_bounds__(THREADS) void chamfer_raw(
    const float* __restrict__ xyz1,
    const float* __restrict__ xyz2,
    float* __restrict__ out)
{
    int bid = blockIdx.x;
    int dir   = bid & 1;                 bid >>= 1;
    int chunk = bid & (FSPLIT - 1);      bid /= FSPLIT;
    int atile = bid & (FATILES - 1);     bid /= FATILES;
    int batch = bid;

    const float* A  = dir ? xyz2 : xyz1;
    const float* Bp = dir ? xyz1 : xyz2;
    float* o = out + (dir ? (B_ * N_) : 0);

    const int a0 = batch * N_ + atile * FAPB + threadIdx.x;

    float ax2[FP], ay2[FP], az2[FP], aww[FP], mm[FP];
#pragma unroll
    for (int p = 0; p < FP; ++p) {
        int idx = a0 + p * THREADS;
        float x = A[3 * idx + 0];
        float y = A[3 * idx + 1];
        float z = A[3 * idx + 2];
        ax2[p] = -2.0f * x;
        ay2[p] = -2.0f * y;
        az2[p] = -2.0f * z;
        aww[p] = fmaf(x, x, fmaf(y, y, z * z));
        mm[p]  = FLT_MAX;
    }

    const float* bp = Bp + 3 * (batch * M_ + chunk * FCHUNK);
#pragma unroll 2
    for (int j = 0; j < FCHUNK; j += 2) {
        float b0x = bp[3 * j + 0], b0y = bp[3 * j + 1], b0z = bp[3 * j + 2];
        float b1x = bp[3 * j + 3], b1y = bp[3 * j + 4], b1z = bp[3 * j + 5];
        float b0w = fmaf(b0x, b0x, fmaf(b0y, b0y, b0z * b0z));
        float b1w = fmaf(b1x, b1x, fmaf(b1y, b1y, b1z * b1z));
#pragma unroll
        for (int p = 0; p < FP; ++p) {
            float t0 = fmaf(ax2[p], b0x, b0w);
            t0 = fmaf(ay2[p], b0y, t0);
            t0 = fmaf(az2[p], b0z, t0);
            float t1 = fmaf(ax2[p], b1x, b1w);
            t1 = fmaf(ay2[p], b1y, t1);
            t1 = fmaf(az2[p], b1z, t1);
            mm[p] = fminf(mm[p], fminf(t0, t1));
        }
    }

#pragma unroll
    for (int p = 0; p < FP; ++p) {
        float d = fmaxf(aww[p] + mm[p], 0.0f);
        atomicMin((unsigned int*)(o + a0 + p * THREADS), __float_as_uint(d));
    }
}

extern "C" void kernel_launch(void* const* d_in, const int* in_sizes, int n_in,
                              void* d_out, int out_size, void* d_ws, size_t ws_size,
                              hipStream_t stream) {
    const float* xyz1 = (const float*)d_in[0];
    const float* xyz2 = (const float*)d_in[1];
    float* out = (float*)d_out;

    // ws layout: Bpack [NTOT*32B] @0, aw [NTOT*4B] after, +8KB pad for
    // prefetch tail over-read (lands in aw, valid memory).
    const size_t bpack_bytes = (size_t)NTOT * 32;
    const size_t need = bpack_bytes + (size_t)NTOT * 4 + 8192;
    if (ws_size >= need) {
        f16*   Bpack = (f16*)d_ws;
        float* aw    = (float*)((char*)d_ws + bpack_bytes);
        prep_kernel<<<(NTOT + 255) / 256, 256, 0, stream>>>(
            xyz1, xyz2, Bpack, aw, out, NSIDE, NTOT);
        chamfer_mfma32<<<NBLOCKS, THREADS, 0, stream>>>(xyz1, xyz2, Bpack, aw, out);
    } else {
        init_kernel<<<(NTOT + 255) / 256, 256, 0, stream>>>(out, NTOT);
        chamfer_raw<<<FNBLOCKS, THREADS, 0, stream>>>(xyz1, xyz2, out);
    }
}